// Round 9
// baseline (129.521 us; speedup 1.0000x reference)
//
#include <hip/hip_runtime.h>
#include <hip/hip_bf16.h>

#define N_EXPERTS 32
#define K_SEL 4
#define IN_C 1024
#define OUT_C 1024
#define BATCH 4096
#define NTOK (BATCH * K_SEL)   // 16384

#define BM 128
#define BN 128
#define BK 64
#define MAX_TILES (N_EXPERTS + NTOK / BM)   // 160 worst case

// workspace layout: wt (bf16, untransposed W) + xb (bf16) + ctrl ints
#define WT_ELEMS (N_EXPERTS * IN_C * OUT_C)          // 33,554,432
#define XB_ELEMS (BATCH * IN_C)                      // 4,194,304
#define CTRL_OFF_BYTES ((size_t)WT_ELEMS * 2 + (size_t)XB_ELEMS * 2)

#define WS_NTILES 0
#define WS_TABLE 8                          // 4 ints per tile
#define WS_ROWLIST (WS_TABLE + MAX_TILES * 4)
#define CTRL_INTS (WS_ROWLIST + NTOK)
// fallback layout additions
#define WS_COUNTS (CTRL_INTS)
#define WS_CURSOR (CTRL_INTS + 32)

typedef __attribute__((ext_vector_type(4))) float f32x4;
typedef __attribute__((ext_vector_type(8))) short bf16x8;
typedef __attribute__((ext_vector_type(8))) unsigned short u16x8;
typedef __attribute__((ext_vector_type(4))) unsigned short u16x4;

__device__ __forceinline__ unsigned short f2bf(float f) {
    union { float f; unsigned u; } v; v.f = f;
    unsigned r = v.u + 0x7fffu + ((v.u >> 16) & 1u);   // RNE
    return (unsigned short)(r >> 16);
}

__device__ __forceinline__ void gload16(const void* g, void* l) {
    __builtin_amdgcn_global_load_lds(
        (const __attribute__((address_space(1))) unsigned int*)g,
        (__attribute__((address_space(3))) unsigned int*)l, 16, 0, 0);
}

// ------- fused prep: bucket (bid 0) + grid-stride pipelined wcopy + xconv -------

#define WCOPY_B0 1
#define WCOPY_NB 2048
#define WCOPY_ITERS 4                        // 2048 blocks x 4 iters x 4096 elems = WT_ELEMS
#define XCONV_B0 (WCOPY_B0 + WCOPY_NB)       // 2049
#define XCONV_NB (XB_ELEMS / 4096)           // 1024
#define PREP_NWG (XCONV_B0 + XCONV_NB)       // 3073

__device__ __forceinline__ void cvt_store16(const f32x4* r, unsigned short* dst) {
    u16x8 o0, o1;
    o0[0] = f2bf(r[0][0]); o0[1] = f2bf(r[0][1]); o0[2] = f2bf(r[0][2]); o0[3] = f2bf(r[0][3]);
    o0[4] = f2bf(r[1][0]); o0[5] = f2bf(r[1][1]); o0[6] = f2bf(r[1][2]); o0[7] = f2bf(r[1][3]);
    o1[0] = f2bf(r[2][0]); o1[1] = f2bf(r[2][1]); o1[2] = f2bf(r[2][2]); o1[3] = f2bf(r[2][3]);
    o1[4] = f2bf(r[3][0]); o1[5] = f2bf(r[3][1]); o1[6] = f2bf(r[3][2]); o1[7] = f2bf(r[3][3]);
    *(u16x8*)dst = o0;
    *(u16x8*)(dst + 8) = o1;
}

__global__ __launch_bounds__(256)
void prep_kernel(const float* __restrict__ x, const float* __restrict__ w,
                 const int* __restrict__ idx,
                 unsigned short* __restrict__ xb, unsigned short* __restrict__ wt,
                 int* __restrict__ ctrl) {
    const int bid = blockIdx.x;
    const int t = threadIdx.x;

    if (bid >= XCONV_B0) {
        // ---- x f32 -> bf16: 16 elems/thread, 4 loads in flight ----
        size_t i = ((size_t)(bid - XCONV_B0) * 256 + t) << 4;
        f32x4 r[4];
        #pragma unroll
        for (int u = 0; u < 4; ++u) r[u] = *(const f32x4*)(x + i + (u << 2));
        cvt_store16(r, xb + i);
    } else if (bid >= WCOPY_B0) {
        // ---- W f32 -> bf16, same layout; grid-stride, 2-deep pipelined ----
        const int b = bid - WCOPY_B0;
        f32x4 ra[4], rb[4];
        size_t i0 = ((size_t)b * 256 + t) << 4;
        const size_t istep = (size_t)WCOPY_NB * 4096;   // elems per grid-iter
        #pragma unroll
        for (int u = 0; u < 4; ++u) ra[u] = *(const f32x4*)(w + i0 + (u << 2));
        #pragma unroll
        for (int j = 0; j < WCOPY_ITERS; ++j) {
            size_t icur = i0 + (size_t)j * istep;
            if (j + 1 < WCOPY_ITERS) {
                size_t inext = icur + istep;
                #pragma unroll
                for (int u = 0; u < 4; ++u) rb[u] = *(const f32x4*)(w + inext + (u << 2));
            }
            cvt_store16(ra, wt + icur);
            #pragma unroll
            for (int u = 0; u < 4; ++u) ra[u] = rb[u];
        }
    } else {
        // ---- bucketing: count -> scan -> table -> scatter, one block ----
        __shared__ int cnt[N_EXPERTS], base[N_EXPERTS], tbase[N_EXPERTS];
        if (t < N_EXPERTS) cnt[t] = 0;
        __syncthreads();
        #pragma unroll 4
        for (int i = 0; i < NTOK / 256; ++i) {
            int e = idx[i * 256 + t] & (N_EXPERTS - 1);
            atomicAdd(&cnt[e], 1);
        }
        __syncthreads();
        if (t == 0) {
            int off = 0, tiles = 0;
            for (int e = 0; e < N_EXPERTS; ++e) {
                base[e] = off;
                tbase[e] = tiles;
                int c = cnt[e];
                tiles += (c + BM - 1) / BM;
                off += c;
            }
            ctrl[WS_NTILES] = tiles;
        }
        __syncthreads();
        if (t < N_EXPERTS) {
            int c = cnt[t], off = base[t], tt = tbase[t];
            for (int u = 0; u < c; u += BM, ++tt) {
                ctrl[WS_TABLE + tt * 4 + 0] = t;
                ctrl[WS_TABLE + tt * 4 + 1] = off + u;
                ctrl[WS_TABLE + tt * 4 + 2] = (c - u) < BM ? (c - u) : BM;
            }
            cnt[t] = off;   // becomes scatter cursor
        }
        __syncthreads();
        #pragma unroll 4
        for (int i = 0; i < NTOK / 256; ++i) {
            int s = i * 256 + t;
            int e = idx[s] & (N_EXPERTS - 1);
            int p = atomicAdd(&cnt[e], 1);
            ctrl[WS_ROWLIST + p] = s;
        }
    }
}

// -------- bf16 grouped GEMM: B from bf16 wt [k][n], register transpose, pipelined --------
// (byte-identical to round-8 proven kernel)

__global__ __launch_bounds__(256, 3)
void gemm_kernel(const unsigned short* __restrict__ xb,
                 const unsigned short* __restrict__ wt,
                 const float* __restrict__ bias,
                 const int* __restrict__ ctrl,
                 float* __restrict__ out) {
    // expert-clustered XCD swizzle: XCD j owns tiles [20j, 20j+20), nb-fastest
    const int swz = ((int)blockIdx.x & 7) * ((MAX_TILES * 8) >> 3) + ((int)blockIdx.x >> 3);
    const int tileIdx = swz >> 3;
    const int ntiles = ctrl[WS_NTILES];
    if (tileIdx >= ntiles) return;
    const int e     = ctrl[WS_TABLE + tileIdx * 4 + 0];
    const int list0 = ctrl[WS_TABLE + tileIdx * 4 + 1];
    const int nrows = ctrl[WS_TABLE + tileIdx * 4 + 2];
    const int n0 = (swz & 7) * BN;

    __shared__ unsigned short As[BM][BK];   // linear; chunk-swizzled via A-source perm
    __shared__ unsigned short Bs[BN][BK];   // rows = n; chunk phys = o ^ (n&7) ^ ((n>>3)&7)
    __shared__ int rowtok[BM];

    const int t = threadIdx.x;
    const int lane = t & 63, wv = t >> 6;

    if (t < BM) {
        int r = t < nrows ? t : nrows - 1;
        rowtok[t] = ctrl[WS_ROWLIST + list0 + r];
    }
    __syncthreads();

    // A staging (proven path): source chunk pre-swizzled
    const int cg = (lane & 7) ^ (lane >> 3);
    const unsigned short* asrc[4];
    #pragma unroll
    for (int i = 0; i < 4; ++i) {
        int row = (wv << 5) + (i << 3) + (lane >> 3);
        asrc[i] = xb + (size_t)(rowtok[row] >> 2) * IN_C + (cg << 3);
    }

    // B staging roles: q = n-quad (4 consecutive n), o = k-octet
    const int q = t & 31, o = t >> 5;
    const unsigned short* bbase = wt + ((size_t)e << 20) + (size_t)(o << 3 << 10) + n0 + (q << 2);

    const int wr = (t >> 7) & 1;          // 2x2 wave grid, 64x64 per wave
    const int wc = (t >> 6) & 1;
    const int lrow = lane & 15, lq = lane >> 4;
    const int afo0 = ((lq) ^ (lrow & 7)) << 4;
    const int afo1 = ((4 + lq) ^ (lrow & 7)) << 4;
    const char* aB = (const char*)&As[wr * 64 + lrow][0];
    const char* bB = (const char*)&Bs[wc * 64 + lrow][0];
    int bfo[2][4];
    #pragma unroll
    for (int kk = 0; kk < 2; ++kk)
        #pragma unroll
        for (int nf = 0; nf < 4; ++nf)
            bfo[kk][nf] = ((((kk << 2) + lq) ^ (lrow & 7) ^ ((2 * nf + (lrow >> 3)) & 7)) << 4);

    f32x4 acc[4][4];
    #pragma unroll
    for (int m = 0; m < 4; ++m)
        #pragma unroll
        for (int n = 0; n < 4; ++n) acc[m][n] = (f32x4)0.f;

    // prologue: B(k=0) loads in flight (8 x u16x4 = 8B/lane, coalesced)
    u16x4 breg[8];
    #pragma unroll
    for (int r = 0; r < 8; ++r)
        breg[r] = *(const u16x4*)(bbase + ((size_t)r << 10));

    for (int k0 = 0; k0 < IN_C; k0 += BK) {
        // barrier #1: all waves finished LDS reads of prior step
        asm volatile("s_waitcnt lgkmcnt(0)" ::: "memory");
        __builtin_amdgcn_s_barrier();
        // A direct-to-LDS (4 VMEM ops; stay in flight past the B write)
        #pragma unroll
        for (int i = 0; i < 4; ++i)
            gload16(asrc[i] + k0, &As[(wv << 5) + (i << 3)][0]);
        __builtin_amdgcn_sched_barrier(0);
        // write B(k) -> Bs: register transpose, no convert (compiler waits vmcnt(4))
        #pragma unroll
        for (int j = 0; j < 4; ++j) {
            const int n = (q << 2) + j;
            const int phys = o ^ (n & 7) ^ ((n >> 3) & 7);
            u16x8 ov;
            #pragma unroll
            for (int r = 0; r < 8; ++r) ov[r] = breg[r][j];
            *(u16x8*)&Bs[n][phys << 3] = ov;
        }
        __builtin_amdgcn_sched_barrier(0);
        if (k0 + BK < IN_C) {
            // prefetch B(k+1); 8 loads stay in flight across the barrier
            const unsigned short* bs2 = bbase + ((size_t)(k0 + BK) << 10);
            #pragma unroll
            for (int r = 0; r < 8; ++r)
                breg[r] = *(const u16x4*)(bs2 + ((size_t)r << 10));
            __builtin_amdgcn_sched_barrier(0);
            asm volatile("s_waitcnt vmcnt(8)" ::: "memory");   // A done, B(k+1) in flight
        } else {
            asm volatile("s_waitcnt vmcnt(0)" ::: "memory");   // last tile: drain A
        }
        asm volatile("s_waitcnt lgkmcnt(0)" ::: "memory");
        __builtin_amdgcn_sched_barrier(0);
        __builtin_amdgcn_s_barrier();      // barrier #2: tile ready
        #pragma unroll
        for (int kk = 0; kk < 2; ++kk) {
            const int afo = kk ? afo1 : afo0;
            bf16x8 a[4], b[4];
            #pragma unroll
            for (int m = 0; m < 4; ++m) a[m] = *(const bf16x8*)(aB + m * 2048 + afo);
            #pragma unroll
            for (int n = 0; n < 4; ++n) b[n] = *(const bf16x8*)(bB + n * 2048 + bfo[kk][n]);
            #pragma unroll
            for (int m = 0; m < 4; ++m)
                #pragma unroll
                for (int n = 0; n < 4; ++n)
                    acc[m][n] = __builtin_amdgcn_mfma_f32_16x16x32_bf16(a[m], b[n], acc[m][n], 0, 0, 0);
        }
    }

    // C/D layout: col = lane&15, row = (lane>>4)*4 + j   [verified m89/m91]
    #pragma unroll
    for (int m = 0; m < 4; ++m) {
        #pragma unroll
        for (int j = 0; j < 4; ++j) {
            int row = wr * 64 + m * 16 + lq * 4 + j;
            if (row < nrows) {
                int s = rowtok[row];
                float* orow = out + (size_t)s * OUT_C;
                #pragma unroll
                for (int n = 0; n < 4; ++n) {
                    int col = n0 + wc * 64 + n * 16 + lrow;
                    float vv = acc[m][n][j] + bias[e * OUT_C + col];
                    orow[col] = vv > 0.f ? vv : 0.f;
                }
            }
        }
    }
}

// ---------------- fallback f32 path (round-1 proven) for small ws ----------------

__global__ void count_kernel(const int* __restrict__ idx, int* __restrict__ ctrl) {
    int s = blockIdx.x * blockDim.x + threadIdx.x;
    if (s < NTOK) atomicAdd(&ctrl[WS_COUNTS + (idx[s] & (N_EXPERTS - 1))], 1);
}

__global__ void scan_kernel(int* __restrict__ ctrl) {
    if (threadIdx.x != 0) return;
    int off = 0, tiles = 0;
    for (int e = 0; e < N_EXPERTS; ++e) {
        int c = ctrl[WS_COUNTS + e];
        ctrl[WS_CURSOR + e] = off;
        for (int t = 0; t < c; t += BM) {
            ctrl[WS_TABLE + tiles * 4 + 0] = e;
            ctrl[WS_TABLE + tiles * 4 + 1] = off + t;
            ctrl[WS_TABLE + tiles * 4 + 2] = (c - t) < BM ? (c - t) : BM;
            ++tiles;
        }
        off += c;
    }
    ctrl[WS_NTILES] = tiles;
}

__global__ void scatter_kernel(const int* __restrict__ idx, int* __restrict__ ctrl) {
    int s = blockIdx.x * blockDim.x + threadIdx.x;
    if (s < NTOK) {
        int e = idx[s] & (N_EXPERTS - 1);
        int p = atomicAdd(&ctrl[WS_CURSOR + e], 1);
        ctrl[WS_ROWLIST + p] = s;
    }
}

__global__ __launch_bounds__(256, 2)
void gemm_f32_kernel(const float* __restrict__ x, const float* __restrict__ w,
                     const float* __restrict__ bias, const int* __restrict__ ctrl,
                     float* __restrict__ out) {
    int ntiles = ctrl[WS_NTILES];
    if ((int)blockIdx.x >= ntiles) return;
    const int e     = ctrl[WS_TABLE + blockIdx.x * 4 + 0];
    const int list0 = ctrl[WS_TABLE + blockIdx.x * 4 + 1];
    const int nrows = ctrl[WS_TABLE + blockIdx.x * 4 + 2];
    const int n0 = blockIdx.y * BN;

    __shared__ unsigned short As2[BM][40];
    __shared__ unsigned short Bs2[BN][40];
    __shared__ int rowtok[BM];

    const int t = threadIdx.x;
    if (t < BM) {
        int r = t < nrows ? t : nrows - 1;
        rowtok[t] = ctrl[WS_ROWLIST + list0 + r];
    }
    __syncthreads();

    const int arow = t >> 1, acol0 = (t & 1) * 16;
    const int brow = t >> 3, bcol0 = (t & 7) * 16;
    const float* xbase = x + (size_t)(rowtok[arow] >> 2) * IN_C + acol0;
    const float* wbase = w + (size_t)e * IN_C * OUT_C + (size_t)brow * OUT_C + n0 + bcol0;

    const int lane = t & 63, wid = t >> 6;
    const int wr = wid >> 1, wc = wid & 1;
    const int lrow = lane & 15, lq = lane >> 4;

    f32x4 acc[4][4];
    #pragma unroll
    for (int m = 0; m < 4; ++m)
        #pragma unroll
        for (int n = 0; n < 4; ++n) acc[m][n] = (f32x4)0.f;

    for (int k0 = 0; k0 < IN_C; k0 += 32) {
        __syncthreads();
        #pragma unroll
        for (int u = 0; u < 4; ++u) {
            f32x4 v = *(const f32x4*)(xbase + k0 + 4 * u);
            ushort4 pk;
            pk.x = f2bf(v[0]); pk.y = f2bf(v[1]); pk.z = f2bf(v[2]); pk.w = f2bf(v[3]);
            *(ushort4*)&As2[arow][acol0 + 4 * u] = pk;
        }
        #pragma unroll
        for (int u = 0; u < 4; ++u) {
            f32x4 v = *(const f32x4*)(wbase + (size_t)k0 * OUT_C + 4 * u);
            Bs2[bcol0 + 4 * u + 0][brow] = f2bf(v[0]);
            Bs2[bcol0 + 4 * u + 1][brow] = f2bf(v[1]);
            Bs2[bcol0 + 4 * u + 2][brow] = f2bf(v[2]);
            Bs2[bcol0 + 4 * u + 3][brow] = f2bf(v[3]);
        }
        __syncthreads();

        bf16x8 a[4], b[4];
        #pragma unroll
        for (int m = 0; m < 4; ++m) a[m] = *(const bf16x8*)&As2[wr * 64 + m * 16 + lrow][lq * 8];
        #pragma unroll
        for (int n = 0; n < 4; ++n) b[n] = *(const bf16x8*)&Bs2[wc * 64 + n * 16 + lrow][lq * 8];
        #pragma unroll
        for (int m = 0; m < 4; ++m)
            #pragma unroll
            for (int n = 0; n < 4; ++n)
                acc[m][n] = __builtin_amdgcn_mfma_f32_16x16x32_bf16(a[m], b[n], acc[m][n], 0, 0, 0);
    }

    #pragma unroll
    for (int m = 0; m < 4; ++m) {
        #pragma unroll
        for (int j = 0; j < 4; ++j) {
            int row = wr * 64 + m * 16 + lq * 4 + j;
            if (row < nrows) {
                int s = rowtok[row];
                float* orow = out + (size_t)s * OUT_C;
                #pragma unroll
                for (int n = 0; n < 4; ++n) {
                    int col = n0 + wc * 64 + n * 16 + lrow;
                    float vv = acc[m][n][j] + bias[e * OUT_C + col];
                    orow[col] = vv > 0.f ? vv : 0.f;
                }
            }
        }
    }
}

// ---------------- launch ----------------

extern "C" void kernel_launch(void* const* d_in, const int* in_sizes, int n_in,
                              void* d_out, int out_size, void* d_ws, size_t ws_size,
                              hipStream_t stream) {
    const float* x    = (const float*)d_in[0];
    const int*   idx  = (const int*)d_in[1];
    const float* w    = (const float*)d_in[2];
    const float* bias = (const float*)d_in[3];
    float* out = (float*)d_out;

    const size_t need = CTRL_OFF_BYTES + (size_t)(CTRL_INTS + 64) * sizeof(int);
    if (ws_size >= need) {
        unsigned short* wt = (unsigned short*)d_ws;
        unsigned short* xb = (unsigned short*)((char*)d_ws + (size_t)WT_ELEMS * 2);
        int* ctrl = (int*)((char*)d_ws + CTRL_OFF_BYTES);

        prep_kernel<<<PREP_NWG, 256, 0, stream>>>(x, w, idx, xb, wt, ctrl);
        gemm_kernel<<<MAX_TILES * 8, 256, 0, stream>>>(xb, wt, bias, ctrl, out);
    } else {
        int* ctrl = (int*)d_ws;
        hipMemsetAsync(ctrl, 0, (CTRL_INTS + 64) * sizeof(int), stream);
        count_kernel<<<NTOK / 256, 256, 0, stream>>>(idx, ctrl);
        scan_kernel<<<1, 64, 0, stream>>>(ctrl);
        scatter_kernel<<<NTOK / 256, 256, 0, stream>>>(idx, ctrl);
        dim3 grid(MAX_TILES, OUT_C / BN);
        gemm_f32_kernel<<<grid, 256, 0, stream>>>(x, w, bias, ctrl, out);
    }
}

// Round 10
// 104.781 us; speedup vs baseline: 1.2361x; 1.2361x over previous
//
#include <hip/hip_runtime.h>
#include <hip/hip_bf16.h>

#define N_EXPERTS 32
#define K_SEL 4
#define IN_C 1024
#define OUT_C 1024
#define BATCH 4096
#define NTOK (BATCH * K_SEL)   // 16384

#define BM 128
#define BN 128
#define BK 64
#define NKT (IN_C / BK)                     // 16 k-tiles
#define MAX_TILES (N_EXPERTS + NTOK / BM)   // 160 worst case

// workspace layout: xb (bf16) then ctrl ints
#define XB_ELEMS (BATCH * IN_C)                      // 4,194,304
#define CTRL_OFF_BYTES ((size_t)XB_ELEMS * 2)

#define WS_NTILES 0
#define WS_TABLE 8                          // 4 ints per tile
#define WS_ROWLIST (WS_TABLE + MAX_TILES * 4)
#define CTRL_INTS (WS_ROWLIST + NTOK)
// fallback layout additions
#define WS_COUNTS (CTRL_INTS)
#define WS_CURSOR (CTRL_INTS + 32)

typedef __attribute__((ext_vector_type(4))) float f32x4;
typedef __attribute__((ext_vector_type(8))) short bf16x8;
typedef __attribute__((ext_vector_type(8))) unsigned short u16x8;

__device__ __forceinline__ unsigned short f2bf(float f) {
    union { float f; unsigned u; } v; v.f = f;
    unsigned r = v.u + 0x7fffu + ((v.u >> 16) & 1u);   // RNE
    return (unsigned short)(r >> 16);
}

__device__ __forceinline__ void gload16(const void* g, void* l) {
    __builtin_amdgcn_global_load_lds(
        (const __attribute__((address_space(1))) unsigned int*)g,
        (__attribute__((address_space(3))) unsigned int*)l, 16, 0, 0);
}

// ---------------- prep: bucket (bid 0) + xconv  (round-6 proven, ~free) ----------------

#define XCONV_B0 1
#define XCONV_NB (XB_ELEMS / 2048)          // 2048
#define PREP_NWG (XCONV_B0 + XCONV_NB)      // 2049

__global__ __launch_bounds__(256)
void prep_kernel(const float* __restrict__ x, const int* __restrict__ idx,
                 unsigned short* __restrict__ xb, int* __restrict__ ctrl) {
    const int bid = blockIdx.x;
    const int t = threadIdx.x;

    if (bid >= XCONV_B0) {
        int i = ((bid - XCONV_B0) * 256 + t) << 3;
        f32x4 v0 = *(const f32x4*)(x + i);
        f32x4 v1 = *(const f32x4*)(x + i + 4);
        u16x8 o;
        o[0] = f2bf(v0[0]); o[1] = f2bf(v0[1]); o[2] = f2bf(v0[2]); o[3] = f2bf(v0[3]);
        o[4] = f2bf(v1[0]); o[5] = f2bf(v1[1]); o[6] = f2bf(v1[2]); o[7] = f2bf(v1[3]);
        *(u16x8*)(xb + i) = o;
    } else {
        __shared__ int cnt[N_EXPERTS], base[N_EXPERTS], tbase[N_EXPERTS];
        if (t < N_EXPERTS) cnt[t] = 0;
        __syncthreads();
        #pragma unroll 4
        for (int i = 0; i < NTOK / 256; ++i) {
            int e = idx[i * 256 + t] & (N_EXPERTS - 1);
            atomicAdd(&cnt[e], 1);
        }
        __syncthreads();
        if (t == 0) {
            int off = 0, tiles = 0;
            for (int e = 0; e < N_EXPERTS; ++e) {
                base[e] = off;
                tbase[e] = tiles;
                int c = cnt[e];
                tiles += (c + BM - 1) / BM;
                off += c;
            }
            ctrl[WS_NTILES] = tiles;
        }
        __syncthreads();
        if (t < N_EXPERTS) {
            int c = cnt[t], off = base[t], tt = tbase[t];
            for (int u = 0; u < c; u += BM, ++tt) {
                ctrl[WS_TABLE + tt * 4 + 0] = t;
                ctrl[WS_TABLE + tt * 4 + 1] = off + u;
                ctrl[WS_TABLE + tt * 4 + 2] = (c - u) < BM ? (c - u) : BM;
            }
            cnt[t] = off;   // becomes scatter cursor
        }
        __syncthreads();
        #pragma unroll 4
        for (int i = 0; i < NTOK / 256; ++i) {
            int s = i * 256 + t;
            int e = idx[s] & (N_EXPERTS - 1);
            int p = atomicAdd(&cnt[e], 1);
            ctrl[WS_ROWLIST + p] = s;
        }
    }
}

// -------- fused grouped GEMM: producer/consumer wave specialization --------
// 512 threads: waves 0-3 = consumers (MFMA only), waves 4-7 = producers
// (A gload_lds + B f32 load -> f2bf -> swizzled ds_write). Double-buffered LDS.
// LDS content / swizzles / fragment offsets byte-identical to the round-8 proven kernel.

__global__ __launch_bounds__(512, 3)
void gemm_kernel(const unsigned short* __restrict__ xb,
                 const float* __restrict__ w,
                 const float* __restrict__ bias,
                 const int* __restrict__ ctrl,
                 float* __restrict__ out) {
    // expert-clustered XCD swizzle
    const int swz = ((int)blockIdx.x & 7) * ((MAX_TILES * 8) >> 3) + ((int)blockIdx.x >> 3);
    const int tileIdx = swz >> 3;
    const int ntiles = ctrl[WS_NTILES];
    if (tileIdx >= ntiles) return;
    const int e     = ctrl[WS_TABLE + tileIdx * 4 + 0];
    const int list0 = ctrl[WS_TABLE + tileIdx * 4 + 1];
    const int nrows = ctrl[WS_TABLE + tileIdx * 4 + 2];
    const int n0 = (swz & 7) * BN;

    __shared__ unsigned short As[2][BM][BK];
    __shared__ unsigned short Bs[2][BN][BK];
    __shared__ int rowtok[BM];

    const int t = threadIdx.x;
    const int lane = t & 63;

    if (t < BM) {
        int r = t < nrows ? t : nrows - 1;
        rowtok[t] = ctrl[WS_ROWLIST + list0 + r];
    }
    __syncthreads();

    if (t >= 256) {
        // ============================ PRODUCER ============================
        const int p = t & 255;
        const int pw = p >> 6;                    // producer wave 0-3
        // A sources: chunk pre-swizzled (proven)
        const int cg = (lane & 7) ^ (lane >> 3);
        const unsigned short* asrc[4];
        #pragma unroll
        for (int i = 0; i < 4; ++i) {
            int row = (pw << 5) + (i << 3) + (lane >> 3);
            asrc[i] = xb + (size_t)(rowtok[row] >> 2) * IN_C + (cg << 3);
        }
        // B roles: q = n-quad, o = k-octet (proven)
        const int q = p & 31, o = p >> 5;
        const float* bbase = w + ((size_t)e << 20) + ((size_t)(o << 3) << 10) + n0 + (q << 2);

        f32x4 brgA[8], brgB[8];
        #pragma unroll
        for (int r = 0; r < 8; ++r)               // prime B(0)
            brgA[r] = *(const f32x4*)(bbase + ((size_t)r << 10));

#define PRODUCE(J, S, CUR, NXT) {                                              \
        const int kof = (J) << 6;                                              \
        _Pragma("unroll")                                                      \
        for (int i = 0; i < 4; ++i)                                            \
            gload16(asrc[i] + kof, &As[S][(pw << 5) + (i << 3)][0]);           \
        __builtin_amdgcn_sched_barrier(0);                                     \
        if ((J) + 1 < NKT) {                                                   \
            const float* bs2 = bbase + ((size_t)(((J) + 1) << 6) << 10);       \
            _Pragma("unroll")                                                  \
            for (int r = 0; r < 8; ++r)                                        \
                NXT[r] = *(const f32x4*)(bs2 + ((size_t)r << 10));             \
        }                                                                      \
        __builtin_amdgcn_sched_barrier(0);                                     \
        _Pragma("unroll")                                                      \
        for (int j = 0; j < 4; ++j) {                                          \
            const int n = (q << 2) + j;                                        \
            const int phys = o ^ (n & 7) ^ ((n >> 3) & 7);                     \
            u16x8 ov;                                                          \
            _Pragma("unroll")                                                  \
            for (int r = 0; r < 8; ++r) ov[r] = f2bf(CUR[r][j]);               \
            *(u16x8*)&Bs[S][n][phys << 3] = ov;                                \
        }                                                                      \
        __builtin_amdgcn_sched_barrier(0);                                     \
        if ((J) + 1 < NKT) asm volatile("s_waitcnt vmcnt(8)" ::: "memory");    \
        else               asm volatile("s_waitcnt vmcnt(0)" ::: "memory");    \
        asm volatile("s_waitcnt lgkmcnt(0)" ::: "memory");                     \
        __builtin_amdgcn_sched_barrier(0);                                     \
        __builtin_amdgcn_s_barrier();                                          \
        __builtin_amdgcn_sched_barrier(0); }

        for (int jj = 0; jj < NKT; jj += 2) {
            PRODUCE(jj,     0, brgA, brgB);
            PRODUCE(jj + 1, 1, brgB, brgA);
        }
        // producers done (16 barriers); consumers do epilogue with no more barriers
    } else {
        // ============================ CONSUMER ============================
        const int wr = (t >> 7) & 1;              // 2x2 wave grid, 64x64 per wave
        const int wc = (t >> 6) & 1;
        const int lrow = lane & 15, lq = lane >> 4;
        const int afo0 = ((lq) ^ (lrow & 7)) << 4;
        const int afo1 = ((4 + lq) ^ (lrow & 7)) << 4;
        const char* aB0 = (const char*)&As[0][wr * 64 + lrow][0];
        const char* aB1 = (const char*)&As[1][wr * 64 + lrow][0];
        const char* bB0 = (const char*)&Bs[0][wc * 64 + lrow][0];
        const char* bB1 = (const char*)&Bs[1][wc * 64 + lrow][0];
        int bfo[2][4];
        #pragma unroll
        for (int kk = 0; kk < 2; ++kk)
            #pragma unroll
            for (int nf = 0; nf < 4; ++nf)
                bfo[kk][nf] = ((((kk << 2) + lq) ^ (lrow & 7) ^ ((2 * nf + (lrow >> 3)) & 7)) << 4);

        f32x4 acc[4][4];
        #pragma unroll
        for (int m = 0; m < 4; ++m)
            #pragma unroll
            for (int n = 0; n < 4; ++n) acc[m][n] = (f32x4)0.f;

#define CONSUME(AB, BB) {                                                      \
        _Pragma("unroll")                                                      \
        for (int kk = 0; kk < 2; ++kk) {                                       \
            const int afo = kk ? afo1 : afo0;                                  \
            bf16x8 a[4], b[4];                                                 \
            _Pragma("unroll")                                                  \
            for (int m = 0; m < 4; ++m) a[m] = *(const bf16x8*)(AB + m * 2048 + afo); \
            _Pragma("unroll")                                                  \
            for (int n = 0; n < 4; ++n) b[n] = *(const bf16x8*)(BB + n * 2048 + bfo[kk][n]); \
            _Pragma("unroll")                                                  \
            for (int m = 0; m < 4; ++m)                                        \
                _Pragma("unroll")                                              \
                for (int n = 0; n < 4; ++n)                                    \
                    acc[m][n] = __builtin_amdgcn_mfma_f32_16x16x32_bf16(a[m], b[n], acc[m][n], 0, 0, 0); \
        } }

#define CBARRIER() { asm volatile("s_waitcnt lgkmcnt(0)" ::: "memory");        \
                     __builtin_amdgcn_sched_barrier(0);                        \
                     __builtin_amdgcn_s_barrier();                             \
                     __builtin_amdgcn_sched_barrier(0); }

        CBARRIER();                                // window 0: buf0 being filled
        for (int jj = 0; jj < NKT; jj += 2) {
            CONSUME(aB0, bB0);                     // tile jj
            CBARRIER();
            CONSUME(aB1, bB1);                     // tile jj+1
            if (jj + 2 < NKT) CBARRIER();
        }
        // 16 barriers total — matches producer

        // epilogue: C/D layout col = lane&15, row = (lane>>4)*4 + j [verified m89/m91]
        #pragma unroll
        for (int m = 0; m < 4; ++m) {
            #pragma unroll
            for (int j = 0; j < 4; ++j) {
                int row = wr * 64 + m * 16 + lq * 4 + j;
                if (row < nrows) {
                    int s = rowtok[row];
                    float* orow = out + (size_t)s * OUT_C;
                    #pragma unroll
                    for (int n = 0; n < 4; ++n) {
                        int col = n0 + wc * 64 + n * 16 + lrow;
                        float vv = acc[m][n][j] + bias[e * OUT_C + col];
                        orow[col] = vv > 0.f ? vv : 0.f;
                    }
                }
            }
        }
    }
}

// ---------------- fallback f32 path (round-1 proven) for small ws ----------------

__global__ void count_kernel(const int* __restrict__ idx, int* __restrict__ ctrl) {
    int s = blockIdx.x * blockDim.x + threadIdx.x;
    if (s < NTOK) atomicAdd(&ctrl[WS_COUNTS + (idx[s] & (N_EXPERTS - 1))], 1);
}

__global__ void scan_kernel(int* __restrict__ ctrl) {
    if (threadIdx.x != 0) return;
    int off = 0, tiles = 0;
    for (int e = 0; e < N_EXPERTS; ++e) {
        int c = ctrl[WS_COUNTS + e];
        ctrl[WS_CURSOR + e] = off;
        for (int t = 0; t < c; t += BM) {
            ctrl[WS_TABLE + tiles * 4 + 0] = e;
            ctrl[WS_TABLE + tiles * 4 + 1] = off + t;
            ctrl[WS_TABLE + tiles * 4 + 2] = (c - t) < BM ? (c - t) : BM;
            ++tiles;
        }
        off += c;
    }
    ctrl[WS_NTILES] = tiles;
}

__global__ void scatter_kernel(const int* __restrict__ idx, int* __restrict__ ctrl) {
    int s = blockIdx.x * blockDim.x + threadIdx.x;
    if (s < NTOK) {
        int e = idx[s] & (N_EXPERTS - 1);
        int p = atomicAdd(&ctrl[WS_CURSOR + e], 1);
        ctrl[WS_ROWLIST + p] = s;
    }
}

__global__ __launch_bounds__(256, 2)
void gemm_f32_kernel(const float* __restrict__ x, const float* __restrict__ w,
                     const float* __restrict__ bias, const int* __restrict__ ctrl,
                     float* __restrict__ out) {
    int ntiles = ctrl[WS_NTILES];
    if ((int)blockIdx.x >= ntiles) return;
    const int e     = ctrl[WS_TABLE + blockIdx.x * 4 + 0];
    const int list0 = ctrl[WS_TABLE + blockIdx.x * 4 + 1];
    const int nrows = ctrl[WS_TABLE + blockIdx.x * 4 + 2];
    const int n0 = blockIdx.y * BN;

    __shared__ unsigned short As2[BM][40];
    __shared__ unsigned short Bs2[BN][40];
    __shared__ int rowtok[BM];

    const int t = threadIdx.x;
    if (t < BM) {
        int r = t < nrows ? t : nrows - 1;
        rowtok[t] = ctrl[WS_ROWLIST + list0 + r];
    }
    __syncthreads();

    const int arow = t >> 1, acol0 = (t & 1) * 16;
    const int brow = t >> 3, bcol0 = (t & 7) * 16;
    const float* xbase = x + (size_t)(rowtok[arow] >> 2) * IN_C + acol0;
    const float* wbase = w + (size_t)e * IN_C * OUT_C + (size_t)brow * OUT_C + n0 + bcol0;

    const int lane = t & 63, wid = t >> 6;
    const int wr = wid >> 1, wc = wid & 1;
    const int lrow = lane & 15, lq = lane >> 4;

    f32x4 acc[4][4];
    #pragma unroll
    for (int m = 0; m < 4; ++m)
        #pragma unroll
        for (int n = 0; n < 4; ++n) acc[m][n] = (f32x4)0.f;

    for (int k0 = 0; k0 < IN_C; k0 += 32) {
        __syncthreads();
        #pragma unroll
        for (int u = 0; u < 4; ++u) {
            f32x4 v = *(const f32x4*)(xbase + k0 + 4 * u);
            ushort4 pk;
            pk.x = f2bf(v[0]); pk.y = f2bf(v[1]); pk.z = f2bf(v[2]); pk.w = f2bf(v[3]);
            *(ushort4*)&As2[arow][acol0 + 4 * u] = pk;
        }
        #pragma unroll
        for (int u = 0; u < 4; ++u) {
            f32x4 v = *(const f32x4*)(wbase + (size_t)k0 * OUT_C + 4 * u);
            Bs2[bcol0 + 4 * u + 0][brow] = f2bf(v[0]);
            Bs2[bcol0 + 4 * u + 1][brow] = f2bf(v[1]);
            Bs2[bcol0 + 4 * u + 2][brow] = f2bf(v[2]);
            Bs2[bcol0 + 4 * u + 3][brow] = f2bf(v[3]);
        }
        __syncthreads();

        bf16x8 a[4], b[4];
        #pragma unroll
        for (int m = 0; m < 4; ++m) a[m] = *(const bf16x8*)&As2[wr * 64 + m * 16 + lrow][lq * 8];
        #pragma unroll
        for (int n = 0; n < 4; ++n) b[n] = *(const bf16x8*)&Bs2[wc * 64 + n * 16 + lrow][lq * 8];
        #pragma unroll
        for (int m = 0; m < 4; ++m)
            #pragma unroll
            for (int n = 0; n < 4; ++n)
                acc[m][n] = __builtin_amdgcn_mfma_f32_16x16x32_bf16(a[m], b[n], acc[m][n], 0, 0, 0);
    }

    #pragma unroll
    for (int m = 0; m < 4; ++m) {
        #pragma unroll
        for (int j = 0; j < 4; ++j) {
            int row = wr * 64 + m * 16 + lq * 4 + j;
            if (row < nrows) {
                int s = rowtok[row];
                float* orow = out + (size_t)s * OUT_C;
                #pragma unroll
                for (int n = 0; n < 4; ++n) {
                    int col = n0 + wc * 64 + n * 16 + lrow;
                    float vv = acc[m][n][j] + bias[e * OUT_C + col];
                    orow[col] = vv > 0.f ? vv : 0.f;
                }
            }
        }
    }
}

// ---------------- launch ----------------

extern "C" void kernel_launch(void* const* d_in, const int* in_sizes, int n_in,
                              void* d_out, int out_size, void* d_ws, size_t ws_size,
                              hipStream_t stream) {
    const float* x    = (const float*)d_in[0];
    const int*   idx  = (const int*)d_in[1];
    const float* w    = (const float*)d_in[2];
    const float* bias = (const float*)d_in[3];
    float* out = (float*)d_out;

    const size_t need = CTRL_OFF_BYTES + (size_t)(CTRL_INTS + 64) * sizeof(int);
    if (ws_size >= need) {
        unsigned short* xb = (unsigned short*)d_ws;
        int* ctrl = (int*)((char*)d_ws + CTRL_OFF_BYTES);

        prep_kernel<<<PREP_NWG, 256, 0, stream>>>(x, idx, xb, ctrl);
        gemm_kernel<<<MAX_TILES * 8, 512, 0, stream>>>(xb, w, bias, ctrl, out);
    } else {
        int* ctrl = (int*)d_ws;
        hipMemsetAsync(ctrl, 0, (CTRL_INTS + 64) * sizeof(int), stream);
        count_kernel<<<NTOK / 256, 256, 0, stream>>>(idx, ctrl);
        scan_kernel<<<1, 64, 0, stream>>>(ctrl);
        scatter_kernel<<<NTOK / 256, 256, 0, stream>>>(idx, ctrl);
        dim3 grid(MAX_TILES, OUT_C / BN);
        gemm_f32_kernel<<<grid, 256, 0, stream>>>(x, w, bias, ctrl, out);
    }
}